// Round 1
// baseline (97.673 us; speedup 1.0000x reference)
//
#include <hip/hip_runtime.h>
#include <math.h>

#define WINDOW 11
#define POLY   3
#define HALF   5
#define TILE   2048
#define TPB    256
#define EPT    8   // elements per thread = TILE / TPB

struct SgCoef {
    float c[WINDOW];          // central FIR taps
    float E[HALF][WINDOW];    // edge fit matrix
};

// ---------------- host-side coefficient computation (double precision) -----

static void invert4(const double M[4][4], double inv[4][4]) {
    double a[4][8];
    for (int i = 0; i < 4; ++i) {
        for (int j = 0; j < 4; ++j) { a[i][j] = M[i][j]; a[i][j + 4] = (i == j) ? 1.0 : 0.0; }
    }
    for (int col = 0; col < 4; ++col) {
        int piv = col;
        for (int r = col + 1; r < 4; ++r)
            if (fabs(a[r][col]) > fabs(a[piv][col])) piv = r;
        if (piv != col)
            for (int j = 0; j < 8; ++j) { double t = a[col][j]; a[col][j] = a[piv][j]; a[piv][j] = t; }
        double d = a[col][col];
        for (int j = 0; j < 8; ++j) a[col][j] /= d;
        for (int r = 0; r < 4; ++r) {
            if (r == col) continue;
            double f = a[r][col];
            for (int j = 0; j < 8; ++j) a[r][j] -= f * a[col][j];
        }
    }
    for (int i = 0; i < 4; ++i)
        for (int j = 0; j < 4; ++j) inv[i][j] = a[i][j + 4];
}

static SgCoef compute_coef() {
    SgCoef co;
    // Central taps: A[i][j] = (i-HALF)^j, c = row 0 of (A^T A)^{-1} A^T
    double A[WINDOW][4];
    for (int i = 0; i < WINDOW; ++i) {
        double p = (double)(i - HALF), v = 1.0;
        for (int j = 0; j < 4; ++j) { A[i][j] = v; v *= p; }
    }
    double N[4][4] = {};
    for (int i = 0; i < 4; ++i)
        for (int j = 0; j < 4; ++j) {
            double s = 0;
            for (int r = 0; r < WINDOW; ++r) s += A[r][i] * A[r][j];
            N[i][j] = s;
        }
    double Ninv[4][4];
    invert4(N, Ninv);
    for (int w = 0; w < WINDOW; ++w) {
        double s = 0;
        for (int j = 0; j < 4; ++j) s += Ninv[0][j] * A[w][j];
        co.c[w] = (float)s;
    }
    // Edge matrix: V[i][j] = i^j, PV = (V^T V)^{-1} V^T, E[h][w] = sum_j h^j PV[j][w]
    double V[WINDOW][4];
    for (int i = 0; i < WINDOW; ++i) {
        double p = (double)i, v = 1.0;
        for (int j = 0; j < 4; ++j) { V[i][j] = v; v *= p; }
    }
    double NV[4][4] = {};
    for (int i = 0; i < 4; ++i)
        for (int j = 0; j < 4; ++j) {
            double s = 0;
            for (int r = 0; r < WINDOW; ++r) s += V[r][i] * V[r][j];
            NV[i][j] = s;
        }
    double NVinv[4][4];
    invert4(NV, NVinv);
    for (int h = 0; h < HALF; ++h) {
        double T[4]; double v = 1.0;
        for (int j = 0; j < 4; ++j) { T[j] = v; v *= (double)h; }
        for (int w = 0; w < WINDOW; ++w) {
            double s = 0;
            for (int j = 0; j < 4; ++j) {
                double pv = 0;
                for (int m = 0; m < 4; ++m) pv += NVinv[j][m] * V[w][m];
                s += T[j] * pv;
            }
            co.E[h][w] = (float)s;
        }
    }
    return co;
}

// ---------------- kernel ---------------------------------------------------

__global__ __launch_bounds__(TPB) void savgol_kernel(
    const float* __restrict__ x, float* __restrict__ out,
    SgCoef coef, int L, int tiles_per_row)
{
    __shared__ float lds[TILE + 16];   // covers [s-8, s+TILE+8)

    const int t    = threadIdx.x;
    const int tile = blockIdx.x;
    const int row  = blockIdx.y;
    const long long rowoff = (long long)row * (long long)L;
    const int s = tile * TILE;
    const float* __restrict__ xr  = x + rowoff;
    float* __restrict__       outr = out + rowoff;

    // Stage [s-8, s+TILE+8) into LDS with float4 loads (16B-aligned: s%2048==0).
    const int NCHUNK = (TILE + 16) / 4;   // 516
    for (int chunk = t; chunk < NCHUNK; chunk += TPB) {
        int gbase = s - 8 + chunk * 4;
        float4 v;
        if (gbase >= 0 && gbase + 3 < L) {
            v = *reinterpret_cast<const float4*>(xr + gbase);
        } else {
            float vv[4];
            #pragma unroll
            for (int q = 0; q < 4; ++q) {
                int g = gbase + q;
                vv[q] = (g >= 0 && g < L) ? xr[g] : 0.0f;
            }
            v = make_float4(vv[0], vv[1], vv[2], vv[3]);
        }
        *reinterpret_cast<float4*>(&lds[chunk * 4]) = v;
    }
    __syncthreads();

    const bool first = (tile == 0);
    const bool last  = (tile == tiles_per_row - 1);

    #pragma unroll
    for (int j = 0; j < EPT; ++j) {
        const int nl = t + j * TPB;       // 0..TILE-1
        const int n  = s + nl;            // global output index in row
        // Interior FIR: out[n] = sum_k c[k] * x[n-5+k]; lds idx of x[n-5] = nl+3
        float acc = 0.0f;
        #pragma unroll
        for (int k = 0; k < WINDOW; ++k)
            acc = fmaf(coef.c[k], lds[nl + 3 + k], acc);
        float val = acc;
        if (first && nl < HALF) {
            // Left edge: out[h] = sum_w E[h][w] * x[w]; lds idx of x[w] = w+8
            float a = 0.0f;
            #pragma unroll
            for (int w = 0; w < WINDOW; ++w)
                a = fmaf(coef.E[nl][w], lds[w + 8], a);
            val = a;
        } else if (last && nl >= TILE - HALF) {
            // Right edge: h = L-1-n; out[n] = sum_w E[h][w] * x[L-1-w]
            int h = (L - 1) - n;          // 0..4
            float a = 0.0f;
            #pragma unroll
            for (int w = 0; w < WINDOW; ++w)
                a = fmaf(coef.E[h][w], lds[(TILE + 7) - w], a);  // (L-1-w)-(s-8), s=L-TILE
            val = a;
        }
        outr[n] = val;
    }
}

// ---------------- launch ---------------------------------------------------

extern "C" void kernel_launch(void* const* d_in, const int* in_sizes, int n_in,
                              void* d_out, int out_size, void* d_ws, size_t ws_size,
                              hipStream_t stream) {
    (void)d_ws; (void)ws_size; (void)n_in;
    const float* x = (const float*)d_in[0];
    float* out = (float*)d_out;

    const int L = 65536;
    const int rows = in_sizes[0] / L;          // 64*16 = 1024
    const int tiles_per_row = L / TILE;        // 32

    SgCoef coef = compute_coef();

    dim3 grid(tiles_per_row, rows);
    dim3 block(TPB);
    savgol_kernel<<<grid, block, 0, stream>>>(x, out, coef, L, tiles_per_row);
}